// Round 1
// 552.365 us; speedup vs baseline: 1.0356x; 1.0356x over previous
//
#include <hip/hip_runtime.h>

// Problem constants
#define Bb 16
#define Nn 16384
#define Ll 192
#define Ee 128
#define Dd 128

// Output element offsets (fp32 elements) within d_out:
// obs:     0          (16*16384*128 = 33554432)
// temp_he: 33554432   (16*192*128   =   393216)
// out:     33947648   (16*128*128   =   262144)
// ti:      34209792   (16*192*16384 = 50331648)
// vi:      84541440   (16*128*16384 = 33554432)   [ti+vi contiguous: 335.5 MB]

// ---------------------------------------------------------------------------
// k_main grid layout (54912 blocks x 256 threads):
//   [    0,   128): qkv   — q,kT,v = relu(var_w) @ W_{q,k,v} + b
//   [  128,  1664): temp  — sin(mark*Wt + bt)
//   [ 1664, 22144): fill  — contiguous float4 zero-stream over ti+vi
//                           (block b owns 16 KB: 4 stores/thread, 1 KB/wave,
//                            consecutive blocks contiguous — fillBuffer pattern)
//   [22144, 54912): obs   — relu(feats @ W_obs + b_obs) * mask
// ---------------------------------------------------------------------------
#define QKV_NB   128
#define TEMP_NB  1536
#define FILL_NB  20480
#define OBS_NB   32768
#define TEMP_B0  (QKV_NB)               // 128
#define FILL_B0  (TEMP_B0 + TEMP_NB)    // 1664
#define OBS_B0   (FILL_B0 + FILL_NB)    // 22144
#define GRID1    (OBS_B0 + OBS_NB)      // 54912

__global__ __launch_bounds__(256) void k_main(
    const float* __restrict__ var_w,
    const float* __restrict__ Wq, const float* __restrict__ bq,
    const float* __restrict__ Wk, const float* __restrict__ bk,
    const float* __restrict__ Wv, const float* __restrict__ bv,
    const float* __restrict__ x, const float* __restrict__ mask,
    const float* __restrict__ ymask,
    const float* __restrict__ W_obs, const float* __restrict__ b_obs,
    const float* __restrict__ mark, const float* __restrict__ Wt,
    const float* __restrict__ bt,
    float* __restrict__ zfill,          // = ti base; ti+vi contiguous
    float* __restrict__ q, float* __restrict__ kT, float* __restrict__ v,
    float* __restrict__ obs, float* __restrict__ temp)
{
    __shared__ float sh[Dd];
    const int tid = threadIdx.x;
    const unsigned bx = blockIdx.x;

    if (bx >= OBS_B0) {
        // obs: one float4 of one row per thread; wave writes 1 KB contiguous,
        // consecutive blocks cover consecutive 4 KB -> streaming-friendly.
        const int g   = (bx - OBS_B0) * 256 + tid;   // over B*N*32
        const int row = g >> 5;
        const int d   = (g & 31) << 2;

        const float m  = mask[row];
        const float xv = x[row];
        const float f1 = 1.0f - m + ymask[row];

        const float4 w0 = *reinterpret_cast<const float4*>(W_obs + d);
        const float4 w1 = *reinterpret_cast<const float4*>(W_obs + Dd + d);
        const float4 bb = *reinterpret_cast<const float4*>(b_obs + d);

        float4 o;
        o.x = fmaxf(fmaf(xv, w0.x, fmaf(f1, w1.x, bb.x)), 0.0f) * m;
        o.y = fmaxf(fmaf(xv, w0.y, fmaf(f1, w1.y, bb.y)), 0.0f) * m;
        o.z = fmaxf(fmaf(xv, w0.z, fmaf(f1, w1.z, bb.z)), 0.0f) * m;
        o.w = fmaxf(fmaf(xv, w0.w, fmaf(f1, w1.w, bb.w)), 0.0f) * m;
        *reinterpret_cast<float4*>(obs + ((size_t)row << 7) + d) = o;
    } else if (bx >= FILL_B0) {
        // zero-fill ti+vi: block owns 1024 contiguous float4 (16 KB).
        float4* p = reinterpret_cast<float4*>(zfill)
                  + ((size_t)(bx - FILL_B0) << 10) + tid;
        const float4 z = make_float4(0.0f, 0.0f, 0.0f, 0.0f);
        p[0]   = z;
        p[256] = z;
        p[512] = z;
        p[768] = z;
    } else if (bx >= TEMP_B0) {
        const int idx = (bx - TEMP_B0) * 256 + tid;  // < 393216
        const int d = idx & 127;
        const int r = idx >> 7;
        temp[idx] = sinf(fmaf(mark[r], Wt[d], bt[d]));
    } else {
        // qkv: one hyperedge row e per block, threads 0..127 active
        const int e = bx;
        if (tid < Dd) sh[tid] = fmaxf(var_w[e * Dd + tid], 0.0f);
        __syncthreads();
        if (tid < Dd) {
            float aq = bq[tid], ak = bk[tid], av = bv[tid];
            #pragma unroll 4
            for (int j = 0; j < Dd; ++j) {
                const float hj = sh[j];
                aq = fmaf(hj, Wq[j * Dd + tid], aq);
                ak = fmaf(hj, Wk[j * Dd + tid], ak);
                av = fmaf(hj, Wv[j * Dd + tid], av);
            }
            q[e * Dd + tid]  = aq;
            kT[tid * Dd + e] = ak;   // transposed for coalesced k_soft reads
            v[e * Dd + tid]  = av;
        }
    }
}

// ---------------------------------------------------------------------------
// k_scatter: runs after k_main (stream-ordered). Writes the ~2*131K one-hot
// nonzeros into the zeroed ti/vi planes and builds the per-(b,e) histogram
// partials (same cnt_part[256][128] layout k_soft expects: block = b*16+f).
// ---------------------------------------------------------------------------
__global__ __launch_bounds__(256) void k_scatter(
    const int* __restrict__ tidx, const int* __restrict__ vidx,
    const float* __restrict__ mask,
    float* __restrict__ ti, float* __restrict__ vi,
    float* __restrict__ cnt_part)
{
    __shared__ float sh[Ee];
    const int tid = threadIdx.x;
    const int g  = blockIdx.x * 256 + tid;   // 65536 threads over B*N/4
    const int b  = g >> 12;                  // 4096 threads per b
    const int n4 = (g & 4095) << 2;

    const int4   t4 = *reinterpret_cast<const int4*>(tidx + b * Nn + n4);
    const int4   v4 = *reinterpret_cast<const int4*>(vidx + b * Nn + n4);
    const float4 m4 = *reinterpret_cast<const float4*>(mask + b * Nn + n4);

    if (tid < Ee) sh[tid] = 0.0f;
    __syncthreads();

    float* tib = ti + (((size_t)b * Ll) << 14);
    float* vib = vi + (((size_t)b * Ee) << 14);

    if (m4.x != 0.0f) {
        atomicAdd(&sh[v4.x], 1.0f);
        tib[((size_t)t4.x << 14) + n4]     = m4.x;
        vib[((size_t)v4.x << 14) + n4]     = m4.x;
    }
    if (m4.y != 0.0f) {
        atomicAdd(&sh[v4.y], 1.0f);
        tib[((size_t)t4.y << 14) + n4 + 1] = m4.y;
        vib[((size_t)v4.y << 14) + n4 + 1] = m4.y;
    }
    if (m4.z != 0.0f) {
        atomicAdd(&sh[v4.z], 1.0f);
        tib[((size_t)t4.z << 14) + n4 + 2] = m4.z;
        vib[((size_t)v4.z << 14) + n4 + 2] = m4.z;
    }
    if (m4.w != 0.0f) {
        atomicAdd(&sh[v4.w], 1.0f);
        tib[((size_t)t4.w << 14) + n4 + 3] = m4.w;
        vib[((size_t)v4.w << 14) + n4 + 3] = m4.w;
    }

    __syncthreads();
    if (tid < Ee) cnt_part[blockIdx.x * Ee + tid] = sh[tid];
}

// ---------------------------------------------------------------------------
// k_soft (unchanged): per-(b,e) fused att-row, count reduction, diag merge,
// softmax, out = attn @ v.
// ---------------------------------------------------------------------------
__global__ __launch_bounds__(128) void k_soft(
    const float* __restrict__ q, const float* __restrict__ kT,
    const float* __restrict__ v, const float* __restrict__ cnt_part,
    const float* __restrict__ thr_p, const float* __restrict__ mc_p,
    const int* __restrict__ nobs_p, float* __restrict__ outp)
{
    __shared__ float qr[Dd];
    __shared__ float attn[Ee];
    __shared__ float red[5];
    const int b = blockIdx.x >> 7;
    const int e = blockIdx.x & 127;
    const int f = threadIdx.x;

    qr[f] = q[e * Dd + f];

    float cp = (f < 16) ? cnt_part[(b * 16 + f) * Ee + e] : 0.0f;
    #pragma unroll
    for (int off = 8; off > 0; off >>= 1) cp += __shfl_xor(cp, off);
    if (f == 0) red[4] = cp;
    __syncthreads();

    float acc0 = 0.0f;
    #pragma unroll 4
    for (int d = 0; d < Dd; ++d) acc0 = fmaf(qr[d], kT[d * Dd + f], acc0);
    float a = acc0 * 0.08838834764831845f;   // 1/sqrt(128)

    if (f == e) {
        const float c = red[4];
        const float thr = *thr_p;
        if (c != 0.0f && a > thr) {
            const float mc  = *mc_p;
            const float aux = c / sqrtf((float)(*nobs_p));
            a = (1.0f - mc) * a + mc * aux;
        }
    }

    float mx = a;
    #pragma unroll
    for (int off = 32; off > 0; off >>= 1) mx = fmaxf(mx, __shfl_xor(mx, off));
    if ((f & 63) == 0) red[f >> 6] = mx;
    __syncthreads();
    mx = fmaxf(red[0], red[1]);

    const float ex = expf(a - mx);
    float s = ex;
    #pragma unroll
    for (int off = 32; off > 0; off >>= 1) s += __shfl_xor(s, off);
    if ((f & 63) == 0) red[2 + (f >> 6)] = s;
    __syncthreads();
    s = red[2] + red[3];

    attn[f] = ex / s;
    __syncthreads();

    const int d = f;
    float acc = 0.0f;
    #pragma unroll 4
    for (int j = 0; j < Ee; ++j) acc = fmaf(attn[j], v[j * Dd + d], acc);
    outp[((size_t)(b * Ee + e) << 7) + d] = acc;
}

// ---------------------------------------------------------------------------
extern "C" void kernel_launch(void* const* d_in, const int* in_sizes, int n_in,
                              void* d_out, int out_size, void* d_ws, size_t ws_size,
                              hipStream_t stream) {
    (void)in_sizes; (void)n_in; (void)out_size; (void)ws_size;

    const float* x      = (const float*)d_in[0];
    const float* mask   = (const float*)d_in[1];
    const float* ymask  = (const float*)d_in[2];
    const float* mark   = (const float*)d_in[3];
    const int*   vidx   = (const int*)d_in[4];
    const int*   tidx   = (const int*)d_in[5];
    const int*   nobs   = (const int*)d_in[6];
    const float* W_obs  = (const float*)d_in[7];
    const float* b_obs  = (const float*)d_in[8];
    const float* W_time = (const float*)d_in[9];
    const float* b_time = (const float*)d_in[10];
    const float* var_w  = (const float*)d_in[11];
    const float* W_q    = (const float*)d_in[12];
    const float* b_q    = (const float*)d_in[13];
    const float* W_k    = (const float*)d_in[14];
    const float* b_k    = (const float*)d_in[15];
    const float* W_v    = (const float*)d_in[16];
    const float* b_v    = (const float*)d_in[17];
    const float* thr    = (const float*)d_in[18];
    const float* mc     = (const float*)d_in[19];

    float* out_base = (float*)d_out;
    float* obs  = out_base;
    float* temp = out_base + 33554432;
    float* attO = out_base + 33947648;
    float* ti   = out_base + 34209792;
    float* vi   = out_base + 84541440;

    // ws layout (fp32): cnt_part[256*128] | q[16384] | kT[16384] | v[16384]
    float* ws       = (float*)d_ws;
    float* cnt_part = ws;
    float* q        = ws + 32768;
    float* kT       = ws + 49152;
    float* v        = ws + 65536;

    k_main<<<GRID1, 256, 0, stream>>>(var_w,
                                      W_q, b_q, W_k, b_k, W_v, b_v,
                                      x, mask, ymask, W_obs, b_obs,
                                      mark, W_time, b_time,
                                      ti /* zfill base: ti+vi contiguous */,
                                      q, kT, v, obs, temp);
    k_scatter<<<256, 256, 0, stream>>>(tidx, vidx, mask, ti, vi, cnt_part);
    k_soft<<<Bb * Ee, Dd, 0, stream>>>(q, kT, v, cnt_part, thr, mc, nobs, attO);
}